// Round 3
// baseline (164.580 us; speedup 1.0000x reference)
//
#include <hip/hip_runtime.h>

#define NCLUSTER 512
#define NC 3
#define HW 65536
#define PPT 4      // pixels per thread
#define BLOCK 256
#define EPS 1e-4f  // > 2*delta; fp32 score rounding delta <= ~2e-5 here

// Certified-exact fp32 fast path: argmin_k d_k == argmin_k t_k,
// t_k = 0.5*||C_k||^2 - x.C_k. Track best1, exact 2nd-best (med3 idiom),
// and fall back to an exact resolve only when the top-2 fp32 gap < EPS.
// The fallback rescans in fp32 and compares only candidates within EPS of
// best1 using exact fp64 direct distances (validated exact in R1, absmax 0).
__global__ __launch_bounds__(BLOCK) void kmeans_assign(
    const float* __restrict__ x,   // [4,3,256,256]
    const float* __restrict__ C,   // [512,3]
    int* __restrict__ out,         // [4,65536]
    int total)
{
    __shared__ float4 lc[NCLUSTER];  // {c0,c1,c2, 0.5*||c||^2}
    for (int k = threadIdx.x; k < NCLUSTER; k += BLOCK) {
        double c0 = C[k * NC + 0];
        double c1 = C[k * NC + 1];
        double c2 = C[k * NC + 2];
        lc[k] = make_float4((float)c0, (float)c1, (float)c2,
                            (float)(0.5 * (c0 * c0 + c1 * c1 + c2 * c2)));
    }
    __syncthreads();

    // Block covers 1024 contiguous pixels (1024 | HW -> single batch per block).
    int base = blockIdx.x * (BLOCK * PPT) + threadIdx.x;   // global pixel id of px 0
    int b = (blockIdx.x * (BLOCK * PPT)) >> 16;            // batch (block-uniform)
    const float* xb = x + (size_t)b * NC * HW;

    float x0[PPT], x1[PPT], x2[PPT], best1[PPT], best2[PPT];
    int idx[PPT];
#pragma unroll
    for (int i = 0; i < PPT; ++i) {
        int p = (base + i * BLOCK) & (HW - 1);
        x0[i] = xb[p];
        x1[i] = xb[p + HW];
        x2[i] = xb[p + 2 * HW];
        best1[i] = 1e30f;
        best2[i] = 1e30f;
        idx[i] = 0;
    }

#pragma unroll 4
    for (int k = 0; k < NCLUSTER; ++k) {
        float4 c = lc[k];   // uniform ds_read_b128 broadcast, amortized over PPT
#pragma unroll
        for (int i = 0; i < PPT; ++i) {
            float t = c.w;
            t = __builtin_fmaf(-x0[i], c.x, t);
            t = __builtin_fmaf(-x1[i], c.y, t);
            t = __builtin_fmaf(-x2[i], c.z, t);
            bool lt = t < best1[i];                              // strict: first index wins
            best2[i] = fminf(fmaxf(t, best1[i]), best2[i]);      // med3 -> exact 2nd-best
            idx[i] = lt ? k : idx[i];
            best1[i] = fminf(t, best1[i]);
        }
    }

#pragma unroll
    for (int i = 0; i < PPT; ++i) {
        if (best2[i] - best1[i] < EPS) {
            // Near-tie: exact resolve. True argmin provably has t < best1+EPS.
            double X0 = x0[i], X1 = x1[i], X2 = x2[i];
            double bd = 1e300;
            int bi = 0;
            for (int k = 0; k < NCLUSTER; ++k) {
                float4 c = lc[k];
                float t = c.w;
                t = __builtin_fmaf(-x0[i], c.x, t);
                t = __builtin_fmaf(-x1[i], c.y, t);
                t = __builtin_fmaf(-x2[i], c.z, t);
                if (t - best1[i] < EPS) {
                    double d0 = X0 - (double)C[k * NC + 0];
                    double d1 = X1 - (double)C[k * NC + 1];
                    double d2 = X2 - (double)C[k * NC + 2];
                    double d = d0 * d0 + d1 * d1 + d2 * d2;
                    if (d < bd) { bd = d; bi = k; }
                }
            }
            idx[i] = bi;
        }
        out[base + i * BLOCK] = idx[i];
    }
}

extern "C" void kernel_launch(void* const* d_in, const int* in_sizes, int n_in,
                              void* d_out, int out_size, void* d_ws, size_t ws_size,
                              hipStream_t stream) {
    const float* x = (const float*)d_in[0];
    const float* C = (const float*)d_in[1];
    int* out = (int*)d_out;

    int total = out_size;  // 262144
    int grid = total / (BLOCK * PPT);  // 256
    kmeans_assign<<<grid, BLOCK, 0, stream>>>(x, C, out, total);
}

// Round 4
// 113.396 us; speedup vs baseline: 1.4514x; 1.4514x over previous
//
#include <hip/hip_runtime.h>

#define NCLUSTER 512
#define NC 3
#define HW 65536
#define PPT 2      // pixels per thread
#define BLOCK 256
#define EPS 1e-4f  // > 2*delta; fp32 score rounding delta <= ~2e-5 here

// Certified-exact fp32 fast path: argmin_k d_k == argmin_k t_k,
// t_k = 0.5*||C_k||^2 - x.C_k. Track best1, exact 2nd-best (med3 idiom);
// when the top-2 fp32 gap < EPS, resolve exactly: rescan in fp32 and compare
// candidates within EPS of best1 by exact fp64 direct distance (validated
// exact vs reference in R1, absmax 0).
__global__ __launch_bounds__(BLOCK) void kmeans_assign(
    const float* __restrict__ x,   // [4,3,256,256]
    const float* __restrict__ C,   // [512,3]
    int* __restrict__ out)         // [4,65536]
{
    __shared__ float4 lc[NCLUSTER];  // {c0,c1,c2, 0.5*||c||^2}
    for (int k = threadIdx.x; k < NCLUSTER; k += BLOCK) {
        double c0 = C[k * NC + 0];
        double c1 = C[k * NC + 1];
        double c2 = C[k * NC + 2];
        lc[k] = make_float4((float)c0, (float)c1, (float)c2,
                            (float)(0.5 * (c0 * c0 + c1 * c1 + c2 * c2)));
    }
    __syncthreads();

    // Block covers BLOCK*PPT = 512 contiguous pixels (512 | HW -> one batch).
    int base = blockIdx.x * (BLOCK * PPT) + threadIdx.x;
    int b = (blockIdx.x * (BLOCK * PPT)) >> 16;   // block-uniform batch id
    const float* xb = x + (size_t)b * NC * HW;

    float x0[PPT], x1[PPT], x2[PPT], best1[PPT], best2[PPT];
    int idx[PPT];
#pragma unroll
    for (int i = 0; i < PPT; ++i) {
        int p = (base + i * BLOCK) & (HW - 1);
        x0[i] = xb[p];
        x1[i] = xb[p + HW];
        x2[i] = xb[p + 2 * HW];
        best1[i] = 1e30f;
        best2[i] = 1e30f;
        idx[i] = 0;
    }

#pragma unroll 8
    for (int k = 0; k < NCLUSTER; ++k) {
        float4 c = lc[k];   // one uniform ds_read_b128, amortized over PPT px
#pragma unroll
        for (int i = 0; i < PPT; ++i) {
            float t = c.w;
            t = __builtin_fmaf(-x0[i], c.x, t);
            t = __builtin_fmaf(-x1[i], c.y, t);
            t = __builtin_fmaf(-x2[i], c.z, t);
            bool lt = t < best1[i];                          // strict: first index wins
            best2[i] = fminf(fmaxf(t, best1[i]), best2[i]);  // med3 -> exact 2nd-best
            idx[i] = lt ? k : idx[i];
            best1[i] = fminf(t, best1[i]);
        }
    }

#pragma unroll
    for (int i = 0; i < PPT; ++i) {
        if (best2[i] - best1[i] < EPS) {
            // Near-tie: exact resolve over candidates within EPS of best1.
            double X0 = x0[i], X1 = x1[i], X2 = x2[i];
            double bd = 1e300;
            int bi = 0;
            for (int k = 0; k < NCLUSTER; ++k) {
                float4 c = lc[k];
                float t = c.w;
                t = __builtin_fmaf(-x0[i], c.x, t);
                t = __builtin_fmaf(-x1[i], c.y, t);
                t = __builtin_fmaf(-x2[i], c.z, t);
                if (t - best1[i] < EPS) {
                    double d0 = X0 - (double)C[k * NC + 0];
                    double d1 = X1 - (double)C[k * NC + 1];
                    double d2 = X2 - (double)C[k * NC + 2];
                    double d = d0 * d0 + d1 * d1 + d2 * d2;
                    if (d < bd) { bd = d; bi = k; }
                }
            }
            idx[i] = bi;
        }
        out[base + i * BLOCK] = idx[i];
    }
}

extern "C" void kernel_launch(void* const* d_in, const int* in_sizes, int n_in,
                              void* d_out, int out_size, void* d_ws, size_t ws_size,
                              hipStream_t stream) {
    const float* x = (const float*)d_in[0];
    const float* C = (const float*)d_in[1];
    int* out = (int*)d_out;

    int total = out_size;                 // 262144
    int grid = total / (BLOCK * PPT);     // 512 blocks -> 2/CU -> 2 waves/SIMD
    kmeans_assign<<<grid, BLOCK, 0, stream>>>(x, C, out);
}

// Round 5
// 111.039 us; speedup vs baseline: 1.4822x; 1.0212x over previous
//
#include <hip/hip_runtime.h>

#define NCLUSTER 512
#define NC 3
#define HW 65536
#define PPT 2      // pixels per thread
#define BLOCK 256
#define GRP 8      // clusters per register group
#define EPS 1e-4f  // > 2*delta; fp32 score rounding delta <= ~2e-5 here

// Certified-exact fp32 fast path: argmin_k d_k == argmin_k t_k,
// t_k = 0.5*||C_k||^2 - x.C_k. Track best1 + exact 2nd-best; near-ties
// (gap < EPS) resolve via exact fp64 direct distance (validated absmax 0).
// K-loop is an explicit ping-pong register double-buffer (A/B groups of 8
// float4) so 8 ds_read_b128 are always in flight under ~224 cyc of VALU —
// the compiler refused to do this on its own (R4: VGPR=32, VALUBusy 23%).
__global__ __launch_bounds__(BLOCK, 2) void kmeans_assign(
    const float* __restrict__ x,   // [4,3,256,256]
    const float* __restrict__ C,   // [512,3]
    int* __restrict__ out)         // [4,65536]
{
    __shared__ float4 lc[NCLUSTER];  // {c0,c1,c2, 0.5*||c||^2}
    for (int k = threadIdx.x; k < NCLUSTER; k += BLOCK) {
        double c0 = C[k * NC + 0];
        double c1 = C[k * NC + 1];
        double c2 = C[k * NC + 2];
        lc[k] = make_float4((float)c0, (float)c1, (float)c2,
                            (float)(0.5 * (c0 * c0 + c1 * c1 + c2 * c2)));
    }
    __syncthreads();

    int base = blockIdx.x * (BLOCK * PPT) + threadIdx.x;
    int b = (blockIdx.x * (BLOCK * PPT)) >> 16;   // block-uniform batch id
    const float* xb = x + (size_t)b * NC * HW;

    float x0[PPT], x1[PPT], x2[PPT], best1[PPT], best2[PPT];
    int idx[PPT];
#pragma unroll
    for (int i = 0; i < PPT; ++i) {
        int p = (base + i * BLOCK) & (HW - 1);
        x0[i] = xb[p];
        x1[i] = xb[p + HW];
        x2[i] = xb[p + 2 * HW];
        best1[i] = 1e30f;
        best2[i] = 1e30f;
        idx[i] = 0;
    }

    float4 A[GRP], B[GRP];
#pragma unroll
    for (int j = 0; j < GRP; ++j) A[j] = lc[j];

#define SCORE(cj, kk)                                                   \
    do {                                                                \
        _Pragma("unroll")                                               \
        for (int i = 0; i < PPT; ++i) {                                 \
            float t = (cj).w;                                           \
            t = __builtin_fmaf(-x0[i], (cj).x, t);                      \
            t = __builtin_fmaf(-x1[i], (cj).y, t);                      \
            t = __builtin_fmaf(-x2[i], (cj).z, t);                      \
            bool lt = t < best1[i];                                     \
            best2[i] = fminf(fmaxf(t, best1[i]), best2[i]);             \
            idx[i] = lt ? (kk) : idx[i];                                \
            best1[i] = fminf(t, best1[i]);                              \
        }                                                               \
    } while (0)

    for (int g = 0; g < NCLUSTER / GRP; g += 2) {
        // prefetch group g+1 into B, then compute group g from A
#pragma unroll
        for (int j = 0; j < GRP; ++j) B[j] = lc[(g + 1) * GRP + j];
#pragma unroll
        for (int j = 0; j < GRP; ++j) SCORE(A[j], g * GRP + j);
        // prefetch group g+2 into A (wraps to 0 at the end, harmless)
#pragma unroll
        for (int j = 0; j < GRP; ++j) A[j] = lc[(((g + 2) & (NCLUSTER / GRP - 1))) * GRP + j];
#pragma unroll
        for (int j = 0; j < GRP; ++j) SCORE(B[j], (g + 1) * GRP + j);
    }
#undef SCORE

#pragma unroll
    for (int i = 0; i < PPT; ++i) {
        if (best2[i] - best1[i] < EPS) {
            // Near-tie: exact resolve over candidates within EPS of best1.
            double X0 = x0[i], X1 = x1[i], X2 = x2[i];
            double bd = 1e300;
            int bi = 0;
            for (int k = 0; k < NCLUSTER; ++k) {
                float4 c = lc[k];
                float t = c.w;
                t = __builtin_fmaf(-x0[i], c.x, t);
                t = __builtin_fmaf(-x1[i], c.y, t);
                t = __builtin_fmaf(-x2[i], c.z, t);
                if (t - best1[i] < EPS) {
                    double d0 = X0 - (double)C[k * NC + 0];
                    double d1 = X1 - (double)C[k * NC + 1];
                    double d2 = X2 - (double)C[k * NC + 2];
                    double d = d0 * d0 + d1 * d1 + d2 * d2;
                    if (d < bd) { bd = d; bi = k; }
                }
            }
            idx[i] = bi;
        }
        out[base + i * BLOCK] = idx[i];
    }
}

extern "C" void kernel_launch(void* const* d_in, const int* in_sizes, int n_in,
                              void* d_out, int out_size, void* d_ws, size_t ws_size,
                              hipStream_t stream) {
    const float* x = (const float*)d_in[0];
    const float* C = (const float*)d_in[1];
    int* out = (int*)d_out;

    int total = out_size;                 // 262144
    int grid = total / (BLOCK * PPT);     // 512 blocks -> 8 waves/CU
    kmeans_assign<<<grid, BLOCK, 0, stream>>>(x, C, out);
}

// Round 6
// 78.454 us; speedup vs baseline: 2.0978x; 1.4154x over previous
//
#include <hip/hip_runtime.h>

#define NCLUSTER 512
#define NC 3
#define HW 65536
#define BLOCK 256
#define EPS 1e-4f  // > 2*delta; fp32 score rounding delta <= ~2e-5 here

// Certified-exact fp32 fast path: argmin_k d_k == argmin_k t_k,
// t_k = 0.5*||C_k||^2 - x.C_k. Track best1 + exact 2nd-best (med3 idiom);
// near-ties (gap < EPS) resolve by exact fp64 direct distance (validated
// absmax 0 in R1). Geometry copies R1 — the only config that hid LDS
// latency: 1 px/thread, grid=1024 (16 waves/CU, 4/SIMD), simple rolled
// loop the compiler pipelines on its own. R4/R5 (2 waves/SIMD + manual
// pipelining) were 2x slower: latency-bound, compiler sank prefetches.
__global__ __launch_bounds__(BLOCK) void kmeans_assign(
    const float* __restrict__ x,   // [4,3,256,256]
    const float* __restrict__ C,   // [512,3]
    int* __restrict__ out,         // [4,65536]
    int total)
{
    __shared__ float4 lc[NCLUSTER];  // {c0,c1,c2, 0.5*||c||^2}
    for (int k = threadIdx.x; k < NCLUSTER; k += BLOCK) {
        double c0 = C[k * NC + 0];
        double c1 = C[k * NC + 1];
        double c2 = C[k * NC + 2];
        lc[k] = make_float4((float)c0, (float)c1, (float)c2,
                            (float)(0.5 * (c0 * c0 + c1 * c1 + c2 * c2)));
    }
    __syncthreads();

    int tid = blockIdx.x * BLOCK + threadIdx.x;
    if (tid >= total) return;

    int p = tid & (HW - 1);
    const float* xb = x + (size_t)(tid >> 16) * NC * HW;
    float x0 = xb[p];
    float x1 = xb[p + HW];
    float x2 = xb[p + 2 * HW];

    float best1 = 1e30f;
    float best2 = 1e30f;
    int idx = 0;

#pragma unroll 4
    for (int k = 0; k < NCLUSTER; ++k) {
        float4 c = lc[k];   // one uniform ds_read_b128 per cluster
        float t = c.w;
        t = __builtin_fmaf(-x0, c.x, t);
        t = __builtin_fmaf(-x1, c.y, t);
        t = __builtin_fmaf(-x2, c.z, t);
        bool lt = t < best1;                        // strict: first index wins
        best2 = fminf(fmaxf(t, best1), best2);      // med3 -> exact 2nd-best
        idx = lt ? k : idx;
        best1 = fminf(t, best1);
    }

    if (best2 - best1 < EPS) {
        // Near-tie: exact resolve over candidates within EPS of best1.
        double X0 = x0, X1 = x1, X2 = x2;
        double bd = 1e300;
        int bi = 0;
        for (int k = 0; k < NCLUSTER; ++k) {
            float4 c = lc[k];
            float t = c.w;
            t = __builtin_fmaf(-x0, c.x, t);
            t = __builtin_fmaf(-x1, c.y, t);
            t = __builtin_fmaf(-x2, c.z, t);
            if (t - best1 < EPS) {
                double d0 = X0 - (double)C[k * NC + 0];
                double d1 = X1 - (double)C[k * NC + 1];
                double d2 = X2 - (double)C[k * NC + 2];
                double d = d0 * d0 + d1 * d1 + d2 * d2;
                if (d < bd) { bd = d; bi = k; }
            }
        }
        idx = bi;
    }

    out[tid] = idx;
}

extern "C" void kernel_launch(void* const* d_in, const int* in_sizes, int n_in,
                              void* d_out, int out_size, void* d_ws, size_t ws_size,
                              hipStream_t stream) {
    const float* x = (const float*)d_in[0];
    const float* C = (const float*)d_in[1];
    int* out = (int*)d_out;

    int total = out_size;              // 262144
    int grid = total / BLOCK;          // 1024 blocks -> 16 waves/CU, 4/SIMD
    kmeans_assign<<<grid, BLOCK, 0, stream>>>(x, C, out, total);
}

// Round 7
// 76.337 us; speedup vs baseline: 2.1560x; 1.0277x over previous
//
#include <hip/hip_runtime.h>

#define NCLUSTER 512
#define NC 3
#define HW 65536
#define BLOCK 256
#define NW 4                     // waves per block = cluster subsets
#define KSUB (NCLUSTER / NW)     // 128 clusters per wave
#define PPT 4                    // pixels per thread (256 px per block)
#define EPS 1e-4f                // > 2*delta; fp32 score rounding delta <= ~2e-5

// Certified-exact fp32 path (validated absmax 0 in R2/R4/R5/R6):
// argmin_k d_k == argmin_k t_k, t_k = 0.5*||C_k||^2 - x.C_k.
// NEW structure: cluster-split x pixel-amortization. Wave w scans clusters
// [128w,128w+128) for 256 block-pixels (4 px/thread) -> each ds_read_b128
// broadcast is amortized over 28 VALU ops, while grid stays 1024 blocks
// (16 waves/CU, 4/SIMD TLP — the only latency-hiding that has worked).
// Cross-wave merge in LDS keeps exact global best1/best2 for the
// certification check; near-ties resolve by exact fp64 direct distance.
__global__ __launch_bounds__(BLOCK) void kmeans_assign(
    const float* __restrict__ x,   // [4,3,256,256]
    const float* __restrict__ C,   // [512,3]
    int* __restrict__ out)         // [4,65536]
{
    __shared__ float4 lc[NCLUSTER];        // {c0,c1,c2, 0.5*||c||^2}  8 KB
    __shared__ float  rb1[NW][BLOCK];      // per-subset best1          4 KB
    __shared__ float  rb2[NW][BLOCK];      // per-subset exact 2nd-best 4 KB
    __shared__ int    ridx[NW][BLOCK];     // per-subset argmin         4 KB

    for (int k = threadIdx.x; k < NCLUSTER; k += BLOCK) {
        double c0 = C[k * NC + 0];
        double c1 = C[k * NC + 1];
        double c2 = C[k * NC + 2];
        lc[k] = make_float4((float)c0, (float)c1, (float)c2,
                            (float)(0.5 * (c0 * c0 + c1 * c1 + c2 * c2)));
    }
    __syncthreads();

    const int w = threadIdx.x >> 6;        // wave id = cluster subset
    const int l = threadIdx.x & 63;        // lane
    const int B0 = blockIdx.x * BLOCK;     // first global pixel of block
    const float* xb = x + (size_t)(B0 >> 16) * NC * HW;  // batch base
    const int pbase = (B0 & (HW - 1)) + l;

    float x0[PPT], x1[PPT], x2[PPT], b1[PPT], b2[PPT];
    int id[PPT];
#pragma unroll
    for (int i = 0; i < PPT; ++i) {
        int p = pbase + i * 64;
        x0[i] = xb[p];
        x1[i] = xb[p + HW];
        x2[i] = xb[p + 2 * HW];
        b1[i] = 1e30f;
        b2[i] = 1e30f;
        id[i] = 0;
    }

    const int k0 = w * KSUB;
#pragma unroll 2
    for (int k = 0; k < KSUB; ++k) {
        float4 c = lc[k0 + k];     // one uniform ds_read_b128, 28 VALU ops follow
#pragma unroll
        for (int i = 0; i < PPT; ++i) {
            float t = c.w;
            t = __builtin_fmaf(-x0[i], c.x, t);
            t = __builtin_fmaf(-x1[i], c.y, t);
            t = __builtin_fmaf(-x2[i], c.z, t);
            bool lt = t < b1[i];                        // strict: first index wins
            b2[i] = fminf(fmaxf(t, b1[i]), b2[i]);      // med3 -> exact 2nd-best
            id[i] = lt ? (k0 + k) : id[i];
            b1[i] = fminf(t, b1[i]);
        }
    }

#pragma unroll
    for (int i = 0; i < PPT; ++i) {
        rb1[w][l + i * 64] = b1[i];
        rb2[w][l + i * 64] = b2[i];
        ridx[w][l + i * 64] = id[i];
    }
    __syncthreads();

    // Merge subsets for pixel t (one pixel per thread), w ascending so the
    // lowest cluster index wins fp32 score ties (matches argmin semantics).
    const int t = threadIdx.x;
    float g1 = rb1[0][t];
    float g2 = rb2[0][t];
    int gi = ridx[0][t];
#pragma unroll
    for (int ww = 1; ww < NW; ++ww) {
        float a1 = rb1[ww][t];
        float a2 = rb2[ww][t];
        int ai = ridx[ww][t];
        bool lt = a1 < g1;
        g2 = lt ? fminf(g1, a2) : fminf(g2, a1);   // exact global 2nd-best
        gi = lt ? ai : gi;
        g1 = fminf(g1, a1);
    }

    if (g2 - g1 < EPS) {
        // Near-tie: exact resolve over candidates within EPS of g1.
        int p = (B0 & (HW - 1)) + t;
        float fx0 = xb[p], fx1 = xb[p + HW], fx2 = xb[p + 2 * HW];
        double X0 = fx0, X1 = fx1, X2 = fx2;
        double bd = 1e300;
        int bi = 0;
        for (int k = 0; k < NCLUSTER; ++k) {
            float4 c = lc[k];
            float s = c.w;
            s = __builtin_fmaf(-fx0, c.x, s);
            s = __builtin_fmaf(-fx1, c.y, s);
            s = __builtin_fmaf(-fx2, c.z, s);
            if (s - g1 < EPS) {
                double d0 = X0 - (double)C[k * NC + 0];
                double d1 = X1 - (double)C[k * NC + 1];
                double d2 = X2 - (double)C[k * NC + 2];
                double d = d0 * d0 + d1 * d1 + d2 * d2;
                if (d < bd) { bd = d; bi = k; }
            }
        }
        gi = bi;
    }

    out[B0 + t] = gi;
}

extern "C" void kernel_launch(void* const* d_in, const int* in_sizes, int n_in,
                              void* d_out, int out_size, void* d_ws, size_t ws_size,
                              hipStream_t stream) {
    const float* x = (const float*)d_in[0];
    const float* C = (const float*)d_in[1];
    int* out = (int*)d_out;

    int total = out_size;              // 262144
    int grid = total / BLOCK;          // 1024 blocks -> 16 waves/CU, 4/SIMD
    kmeans_assign<<<grid, BLOCK, 0, stream>>>(x, C, out);
}

// Round 8
// 32.239 us; speedup vs baseline: 5.1050x; 2.3678x over previous
//
#include <hip/hip_runtime.h>

#define NCLUSTER 512
#define NC 3
#define HW 65536
#define BLOCK 256
#define NW 4                     // waves per block = cluster subsets
#define KSUB (NCLUSTER / NW)     // 128 clusters per wave
#define PPT 4                    // pixels per thread (256 px per block)
#define EPS 1e-4f                // >> 2*delta (delta <= ~1.5e-5 for |t|<=70)

// Certified-exact fp32 path: argmin_k d_k == argmin_k t_k,
// t_k = 0.5*||C_k||^2 - x.C_k; exact global top-2 (b2 via v_med3) certifies
// the fp32 argmin when gap >= EPS. NEW in R8: near-tie pixels are COMPACTED
// into an LDS queue and resolved wave-cooperatively in exact fp64 (64 lanes
// x 8 clusters + shfl_xor argmin butterfly) — kills the divergent 512-iter
// per-thread fallback tail that capped R6/R7 (85% of blocks had >=1 trigger).
__global__ __launch_bounds__(BLOCK) void kmeans_assign(
    const float* __restrict__ x,   // [4,3,256,256]
    const float* __restrict__ C,   // [512,3]
    int* __restrict__ out)         // [4,65536]
{
    __shared__ float4 lc[NCLUSTER];        // {c0,c1,c2, 0.5*||c||^2}  8 KB
    __shared__ float  rb1[NW][BLOCK];      // per-subset best1          4 KB
    __shared__ float  rb2[NW][BLOCK];      // per-subset exact 2nd-best 4 KB
    __shared__ int    ridx[NW][BLOCK];     // per-subset argmin         4 KB
    __shared__ int    qpx[BLOCK];          // near-tie pixel queue      1 KB
    __shared__ int    qcnt;

    if (threadIdx.x == 0) qcnt = 0;
    for (int k = threadIdx.x; k < NCLUSTER; k += BLOCK) {
        double c0 = C[k * NC + 0];
        double c1 = C[k * NC + 1];
        double c2 = C[k * NC + 2];
        lc[k] = make_float4((float)c0, (float)c1, (float)c2,
                            (float)(0.5 * (c0 * c0 + c1 * c1 + c2 * c2)));
    }
    __syncthreads();

    const int w = threadIdx.x >> 6;        // wave id = cluster subset
    const int l = threadIdx.x & 63;        // lane
    const int B0 = blockIdx.x * BLOCK;     // first global pixel of block
    const int pB = B0 & (HW - 1);          // pixel base within batch
    const float* xb = x + (size_t)(B0 >> 16) * NC * HW;

    float x0[PPT], x1[PPT], x2[PPT], b1[PPT], b2[PPT];
    int id[PPT];
#pragma unroll
    for (int i = 0; i < PPT; ++i) {
        int p = pB + l + i * 64;
        x0[i] = xb[p];
        x1[i] = xb[p + HW];
        x2[i] = xb[p + 2 * HW];
        b1[i] = 1e30f;
        b2[i] = 1e30f;
        id[i] = 0;
    }

    const int k0 = w * KSUB;
#pragma unroll 4
    for (int k = 0; k < KSUB; ++k) {
        float4 c = lc[k0 + k];   // one uniform ds_read_b128, 28 VALU ops follow
#pragma unroll
        for (int i = 0; i < PPT; ++i) {
            float t = c.w;
            t = __builtin_fmaf(-x0[i], c.x, t);
            t = __builtin_fmaf(-x1[i], c.y, t);
            t = __builtin_fmaf(-x2[i], c.z, t);
            bool lt = t < b1[i];                              // strict: first k wins
            b2[i] = __builtin_amdgcn_fmed3f(t, b1[i], b2[i]); // exact 2nd-best, 1 op
            id[i] = lt ? (k0 + k) : id[i];
            b1[i] = fminf(t, b1[i]);
        }
    }

#pragma unroll
    for (int i = 0; i < PPT; ++i) {
        rb1[w][l + i * 64] = b1[i];
        rb2[w][l + i * 64] = b2[i];
        ridx[w][l + i * 64] = id[i];
    }
    __syncthreads();

    // Merge subsets for pixel t (one px per thread), w ascending so the
    // lowest cluster index wins on equal fp32 scores (argmin semantics).
    {
        const int t = threadIdx.x;
        float g1 = rb1[0][t];
        float g2 = rb2[0][t];
        int gi = ridx[0][t];
#pragma unroll
        for (int ww = 1; ww < NW; ++ww) {
            float a1 = rb1[ww][t];
            float a2 = rb2[ww][t];
            int ai = ridx[ww][t];
            bool lt = a1 < g1;
            g2 = lt ? fminf(g1, a2) : fminf(g2, a1);   // exact global 2nd-best
            gi = lt ? ai : gi;
            g1 = fminf(g1, a1);
        }
        if (g2 - g1 < EPS) {
            qpx[atomicAdd(&qcnt, 1)] = t;   // near-tie: defer to exact resolve
        } else {
            out[B0 + t] = gi;               // certified correct
        }
    }
    __syncthreads();

    // Wave-cooperative exact resolve: one queued pixel per wave at a time,
    // 64 lanes x 8 clusters, exact fp64 direct distances (the form validated
    // absmax-0 vs reference in R1), smallest-k tie-break.
    const int n = qcnt;
    for (int e = w; e < n; e += NW) {
        const int t = qpx[e];
        const int p = pB + t;
        double X0 = (double)xb[p];
        double X1 = (double)xb[p + HW];
        double X2 = (double)xb[p + 2 * HW];
        double bd = 1e300;
        int bi = 0;
#pragma unroll
        for (int j = 0; j < NCLUSTER / 64; ++j) {
            int k = j * 64 + l;              // ascending per lane
            float4 c = lc[k];
            double d0 = X0 - (double)c.x;
            double d1 = X1 - (double)c.y;
            double d2 = X2 - (double)c.z;
            double d = d0 * d0 + d1 * d1 + d2 * d2;
            if (d < bd) { bd = d; bi = k; }  // strict: smallest k in lane wins
        }
#pragma unroll
        for (int m = 1; m < 64; m <<= 1) {   // butterfly argmin reduce
            double od = __shfl_xor(bd, m, 64);
            int oi = __shfl_xor(bi, m, 64);
            bool take = (od < bd) || (od == bd && oi < bi);
            bd = take ? od : bd;
            bi = take ? oi : bi;
        }
        if (l == 0) out[B0 + t] = bi;
    }
}

extern "C" void kernel_launch(void* const* d_in, const int* in_sizes, int n_in,
                              void* d_out, int out_size, void* d_ws, size_t ws_size,
                              hipStream_t stream) {
    const float* x = (const float*)d_in[0];
    const float* C = (const float*)d_in[1];
    int* out = (int*)d_out;

    int total = out_size;              // 262144
    int grid = total / BLOCK;          // 1024 blocks -> 16 waves/CU, 4/SIMD
    kmeans_assign<<<grid, BLOCK, 0, stream>>>(x, C, out);
}